// Round 10
// baseline (123.966 us; speedup 1.0000x reference)
//
#include <hip/hip_runtime.h>

// AdaptiveAngleConv round 10:
//   pass 1: xt_build — x fp32 -> bf16 granules x_t[b][h][slot][w][8ci]
//   pass 2: build_A  — canonical weights + bias as 37th K-step
//   pass 3: aconv_v10 — 256 blocks x 512 thr, 8 waves = (angle, row),
//           wave tile M=64 x N=128 (mf=2, nf=4): 6 ds_read per 8 MFMA,
//           1-deep register prefetch of fragments, gll staging (0 VGPRs),
//           full-width 4-row ring, bias-kstep, NT stores, lgkm/vmcnt barriers.
// Fallback (small ws_size): R7 kernel (101 us).

#define CIN 64
#define COUT 64
#define HH 128
#define WW 128
#define NB 16
#define HW (HH*WW)

typedef short bf16x8 __attribute__((ext_vector_type(8)));
typedef float f32x16 __attribute__((ext_vector_type(16)));
#define AS1 __attribute__((address_space(1)))
#define AS3 __attribute__((address_space(3)))

__device__ __constant__ unsigned char DHI_d[4][9] = {
  {0,0,0,1,1,1,2,2,2},
  {0,0,1,0,1,2,1,2,2},
  {0,1,2,0,1,2,0,1,2},
  {1,2,2,0,1,2,0,0,1},
};
__device__ __constant__ unsigned short DWB_d[4][9] = {
  {0,16,32,0,16,32,0,16,32},
  {16,32,32,0,16,32,0,0,16},
  {32,32,32,16,16,16,0,0,0},
  {32,32,16,32,16,0,16,0,0},
};

static __device__ __forceinline__ unsigned short f2bf(float f) {
  unsigned u = __builtin_bit_cast(unsigned, f);
  return (unsigned short)((u + 0x7FFFu + ((u >> 16) & 1u)) >> 16);
}
static __device__ __forceinline__ unsigned pk2(float lo, float hi) {
  return (unsigned)f2bf(lo) | ((unsigned)f2bf(hi) << 16);
}

// ---- pass 1: x transpose/convert. granule idx = ((b*HH+h)*8+slot)*128 + w ----
__global__ __launch_bounds__(256) void xt_build_kernel(const float* __restrict__ x,
                                                       unsigned short* __restrict__ xt) {
  const int gid = blockIdx.x * 256 + threadIdx.x;   // 2,097,152
  const int w = gid & 127;
  const int h = (gid >> 7) & 127;
  const int slot = (gid >> 14) & 7;
  const int b = gid >> 17;
  const float* xp = x + ((size_t)(b * CIN + slot * 8) * HH + h) * WW + w;
  uint4 u;
  u.x = pk2(xp[0], xp[HW]);
  u.y = pk2(xp[2 * HW], xp[3 * HW]);
  u.z = pk2(xp[4 * HW], xp[5 * HW]);
  u.w = pk2(xp[6 * HW], xp[7 * HW]);
  const size_t idx = ((size_t)(b * HH + h) * 8 + slot) * 128 + w;
  *(uint4*)((unsigned char*)xt + idx * 16) = u;
}

// ---- pass 2: canonical A + bias kstep. 37,888 bf16 ----
__global__ void build_A_kernel(const float* __restrict__ wgt,
                               const float* __restrict__ bias,
                               unsigned short* __restrict__ A) {
  const int e = blockIdx.x * 256 + threadIdx.x;
  const int j = e & 7;
  const int cm = (e >> 3) & 63;
  const int half = (e >> 9) & 1;
  const int kc = e >> 10;
  if (kc < 36) {
    const int s = kc >> 2, q = kc & 3;
    const int ci = q * 16 + half * 8 + j;
    A[e] = f2bf(wgt[(cm * CIN + ci) * 9 + s]);
  } else if (kc == 36) {
    A[e] = (half == 0 && j == 0) ? f2bf(bias[cm]) : (unsigned short)0;
  }
}

// =======================  v10 main kernel  =======================
#define V9_SLOT 2080
#define V9_ROW  16640               // 8 * V9_SLOT
#define V9_XOFF 75776               // 37 kc * 2048 B
#define V9_LDS  (V9_XOFF + 4 * V9_ROW)   // 142,336 B

__global__ __launch_bounds__(512, 2) void aconv_v10_kernel(
    const unsigned short* __restrict__ xt,
    const unsigned short* __restrict__ Ag,
    float* __restrict__ out)
{
  __shared__ __align__(16) unsigned char lds[V9_LDS];

  const int tid = threadIdx.x;
  const int lane = tid & 63;
  const int wid = tid >> 6;          // 8 waves
  const int a   = wid >> 1;          // angle
  const int row = wid & 1;           // row within 2-row tile
  const int half = lane >> 5;
  const int ln = lane & 31;

  const int b   = blockIdx.x >> 4;
  const int rem = blockIdx.x & 15;
  const int hbase = rem * 8;

  const unsigned char* Agb = (const unsigned char*)Ag;
  const unsigned char* xtb = (const unsigned char*)xt;
  AS3 unsigned char* ldsa = (AS3 unsigned char*)lds;
  const uint4 z4 = {0u, 0u, 0u, 0u};

  // ---- prologue: A (74 gll), border zeros, x rows hbase-1..+2 (64 gll) ----
  #pragma unroll
  for (int j = 0; j < 10; ++j) {
    const int i = wid + j * 8;
    if (i < 74)
      __builtin_amdgcn_global_load_lds(
          (const AS1 unsigned*)(Agb + i * 1024 + lane * 16),
          (AS3 unsigned*)(ldsa + i * 1024), 16, 0, 0);
  }
  if (tid < 64) {
    const int rs = tid >> 4, cs = (tid >> 1) & 7, side = tid & 1;
    *(uint4*)(lds + V9_XOFF + rs * V9_ROW + cs * V9_SLOT + side * 129 * 16) = z4;
  }
  #pragma unroll
  for (int j = 0; j < 8; ++j) {
    const int c = wid + j * 8;         // 64 combos: 4 rows x 8 slots x 2 halves
    const int rr = c >> 4;
    const int s  = (c >> 1) & 7;
    const int k  = c & 1;
    const int gh = hbase - 1 + rr;
    const unsigned dst = (unsigned)(V9_XOFF + rr * V9_ROW + s * V9_SLOT + 16 + k * 1024);
    if (gh >= 0) {
      __builtin_amdgcn_global_load_lds(
          (const AS1 unsigned*)(xtb + ((size_t)((b * HH + gh) * 8 + s) * 128 + k * 64) * 16 + lane * 16),
          (AS3 unsigned*)(ldsa + dst), 16, 0, 0);
    } else {
      *(uint4*)(lds + dst + lane * 16) = z4;
    }
  }
  __syncthreads();

  const unsigned char* Asb = lds + (unsigned)(half * 1024 + ln * 16);
  const unsigned char* Bsb = lds + V9_XOFF + (unsigned)(half * V9_SLOT + ln * 16);

  bf16x8 ob = (bf16x8)(short)0;      // one-hot B frag for bias kstep
  if (half == 0) ob[0] = (short)0x3F80;

  #pragma unroll 1
  for (int it = 0; it < 4; ++it) {
    unsigned boff_t[9];
    #pragma unroll
    for (int s = 0; s < 9; ++s)
      boff_t[s] = (unsigned)DWB_d[a][s]
                + (unsigned)(((it * 2 + row + (int)DHI_d[a][s]) & 3) * V9_ROW);

    f32x16 acc[2][4];
    #pragma unroll
    for (int mf = 0; mf < 2; ++mf)
      #pragma unroll
      for (int nf = 0; nf < 4; ++nf) acc[mf][nf] = (f32x16)(0.f);

    // current fragments (kc = 0)
    bf16x8 ca0 = *(const bf16x8*)(Asb);
    bf16x8 ca1 = *(const bf16x8*)(Asb + 512);
    unsigned bb0 = boff_t[0];
    bf16x8 cb0 = *(const bf16x8*)(Bsb + bb0);
    bf16x8 cb1 = *(const bf16x8*)(Bsb + bb0 + 512);
    bf16x8 cb2 = *(const bf16x8*)(Bsb + bb0 + 1024);
    bf16x8 cb3 = *(const bf16x8*)(Bsb + bb0 + 1536);

    #pragma unroll
    for (int kc = 0; kc < 36; ++kc) {
      bf16x8 na0, na1, nb0, nb1, nb2, nb3;
      if (kc < 35) {
        const int kn = kc + 1;
        na0 = *(const bf16x8*)(Asb + kn * 2048);
        na1 = *(const bf16x8*)(Asb + kn * 2048 + 512);
        const unsigned bb = boff_t[kn >> 2] + (unsigned)((kn & 3) * 2 * V9_SLOT);
        nb0 = *(const bf16x8*)(Bsb + bb);
        nb1 = *(const bf16x8*)(Bsb + bb + 512);
        nb2 = *(const bf16x8*)(Bsb + bb + 1024);
        nb3 = *(const bf16x8*)(Bsb + bb + 1536);
      } else {  // prefetch bias-kstep A
        na0 = *(const bf16x8*)(Asb + 36 * 2048);
        na1 = *(const bf16x8*)(Asb + 36 * 2048 + 512);
      }
      acc[0][0] = __builtin_amdgcn_mfma_f32_32x32x16_bf16(ca0, cb0, acc[0][0], 0, 0, 0);
      acc[1][0] = __builtin_amdgcn_mfma_f32_32x32x16_bf16(ca1, cb0, acc[1][0], 0, 0, 0);
      acc[0][1] = __builtin_amdgcn_mfma_f32_32x32x16_bf16(ca0, cb1, acc[0][1], 0, 0, 0);
      acc[1][1] = __builtin_amdgcn_mfma_f32_32x32x16_bf16(ca1, cb1, acc[1][1], 0, 0, 0);
      acc[0][2] = __builtin_amdgcn_mfma_f32_32x32x16_bf16(ca0, cb2, acc[0][2], 0, 0, 0);
      acc[1][2] = __builtin_amdgcn_mfma_f32_32x32x16_bf16(ca1, cb2, acc[1][2], 0, 0, 0);
      acc[0][3] = __builtin_amdgcn_mfma_f32_32x32x16_bf16(ca0, cb3, acc[0][3], 0, 0, 0);
      acc[1][3] = __builtin_amdgcn_mfma_f32_32x32x16_bf16(ca1, cb3, acc[1][3], 0, 0, 0);
      ca0 = na0; ca1 = na1; cb0 = nb0; cb1 = nb1; cb2 = nb2; cb3 = nb3;
    }
    {  // bias kstep: one-hot B adds bias[cm] to every column
      #pragma unroll
      for (int nf = 0; nf < 4; ++nf) {
        acc[0][nf] = __builtin_amdgcn_mfma_f32_32x32x16_bf16(ca0, ob, acc[0][nf], 0, 0, 0);
        acc[1][nf] = __builtin_amdgcn_mfma_f32_32x32x16_bf16(ca1, ob, acc[1][nf], 0, 0, 0);
      }
    }

    // NT stores (drain under barriers / next K-loop)
    const int hout = hbase + it * 2 + row;
    #pragma unroll
    for (int mf = 0; mf < 2; ++mf)
      #pragma unroll
      for (int nf = 0; nf < 4; ++nf) {
        const f32x16 v = acc[mf][nf];
        float* op = out + (((size_t)(a * NB + b) * COUT + mf * 32 + 4 * half) * HH
                           + hout) * WW + nf * 32 + ln;
        #pragma unroll
        for (int g = 0; g < 16; ++g)
          __builtin_nontemporal_store(v[g], op + (size_t)((g & 3) + 8 * (g >> 2)) * HW);
      }

    // barrier 1: all waves done reading the ring (lgkm only)
    asm volatile("s_waitcnt lgkmcnt(0)" ::: "memory");
    __builtin_amdgcn_s_barrier();

    if (it < 3) {
      // restage 2 rows via gll (4 instrs/wave): rows hbase+2it+3, +4
      #pragma unroll
      for (int j = 0; j < 4; ++j) {
        const int c = wid + j * 8;     // 32 combos: 2 rows x 8 slots x 2 halves
        const int rr = c >> 4;
        const int s  = (c >> 1) & 7;
        const int k  = c & 1;
        const int gh = hbase + it * 2 + 3 + rr;
        const unsigned dst = (unsigned)(V9_XOFF + ((it * 2 + rr) & 3) * V9_ROW
                                        + s * V9_SLOT + 16 + k * 1024);
        if (gh < HH) {
          __builtin_amdgcn_global_load_lds(
              (const AS1 unsigned*)(xtb + ((size_t)((b * HH + gh) * 8 + s) * 128 + k * 64) * 16 + lane * 16),
              (AS3 unsigned*)(ldsa + dst), 16, 0, 0);
        } else {
          *(uint4*)(lds + dst + lane * 16) = z4;
        }
      }
      // barrier 2: publish (gll tracked by vmcnt)
      asm volatile("s_waitcnt vmcnt(0) lgkmcnt(0)" ::: "memory");
      __builtin_amdgcn_s_barrier();
    }
  }
}

// =======================  R7 fallback kernel  =======================
#define R7_SLOT 1072
#define R7_ROW  8576
#define R7_XOFF 73728
#define R7_LDS  (R7_XOFF + 4 * R7_ROW)

static __device__ __forceinline__ void lgkm_barrier() {
  asm volatile("s_waitcnt lgkmcnt(0)" ::: "memory");
  __builtin_amdgcn_s_barrier();
}

__global__ __launch_bounds__(512) void aconv_v7_kernel(
    const float* __restrict__ x,
    const unsigned short* __restrict__ Ag,
    const float* __restrict__ bias,
    float* __restrict__ out)
{
  __shared__ __align__(16) unsigned char lds[R7_LDS];

  const int tid = threadIdx.x;
  const int lane = tid & 63;
  const int wid = tid >> 6;
  const int a   = wid >> 1;
  const int row = wid & 1;
  const int half = lane >> 5;
  const int ln = lane & 31;

  const int blk = blockIdx.x;
  const int b   = blk >> 4;
  const int rem = blk & 15;
  const int hbase = rem * 8;

  float bv[2][16];
  #pragma unroll
  for (int mf = 0; mf < 2; ++mf)
    #pragma unroll
    for (int g = 0; g < 16; ++g)
      bv[mf][g] = bias[mf * 32 + (g & 3) + 8 * (g >> 2) + 4 * half];

  int dhi[9]; unsigned dwb[9];
  #pragma unroll
  for (int s = 0; s < 9; ++s) { dhi[s] = DHI_d[a][s]; dwb[s] = DWB_d[a][s]; }

  {
    const uint4* Ag4 = (const uint4*)Ag;
    uint4* As4 = (uint4*)lds;
    #pragma unroll
    for (int i = 0; i < 9; ++i) As4[tid + i * 512] = Ag4[tid + i * 512];
  }

  float gv[5][8];
  unsigned gdst[5];
  bool gval[5];

  #pragma unroll
  for (int i = 0; i < 5; ++i) {
    const int g = tid + i * 512;
    const bool v = g < 2112;
    const int rg = g / 528;
    const int rest = g - rg * 528;
    const int slot = rest / 66;
    const int wI = rest - slot * 66;
    const int hx = hbase - 1 + rg;
    const int gw = -1 + wI;
    const bool inb = v && ((unsigned)hx < HH) && ((unsigned)gw < WW);
    const float* xp = x + (size_t)(b * CIN + slot * 8) * HW + (size_t)hx * WW + gw;
    gval[i] = v;
    gdst[i] = (unsigned)(R7_XOFF + rg * R7_ROW + slot * R7_SLOT + wI * 16);
    #pragma unroll
    for (int q = 0; q < 8; ++q) gv[i][q] = inb ? xp[(size_t)q * HW] : 0.f;
  }
  #pragma unroll
  for (int i = 0; i < 5; ++i)
    if (gval[i]) {
      uint4 u;
      u.x = pk2(gv[i][0], gv[i][1]); u.y = pk2(gv[i][2], gv[i][3]);
      u.z = pk2(gv[i][4], gv[i][5]); u.w = pk2(gv[i][6], gv[i][7]);
      *(uint4*)(lds + gdst[i]) = u;
    }
  __syncthreads();

  const unsigned char* Asb = lds + (unsigned)(half * 1024 + ln * 16);
  const unsigned char* Bsb = lds + R7_XOFF + (unsigned)(half * R7_SLOT + ln * 16);

  #pragma unroll 1
  for (int ti = 0; ti < 8; ++ti) {
    const int wh = ti >> 2, it = ti & 3;
    const int w0 = wh * 64;

    unsigned boff_t[9];
    {
      unsigned rowoff[3];
      #pragma unroll
      for (int dh = 0; dh < 3; ++dh)
        rowoff[dh] = (unsigned)(((2 * it + row + dh) & 3) * R7_ROW);
      #pragma unroll
      for (int s = 0; s < 9; ++s) boff_t[s] = dwb[s] + rowoff[dhi[s]];
    }

    const bool pf2 = (it < 3);
    const bool pf4 = (it == 3) && (wh == 0);
    const int ngran = pf2 ? 1056 : (pf4 ? 2112 : 0);
    if (ngran) {
      const int itv = pf4 ? -2 : it;
      const int w0n = pf4 ? 64 : w0;
      #pragma unroll
      for (int i = 0; i < 5; ++i) {
        const int g = tid + i * 512;
        const bool v = g < ngran;
        const int rg = g / 528;
        const int rest = g - rg * 528;
        const int slot = rest / 66;
        const int wI = rest - slot * 66;
        const int hx = hbase + 2 * itv + 3 + rg;
        const int ps = (2 * itv + 4 + rg) & 3;
        const int gw = w0n - 1 + wI;
        const bool inb = v && ((unsigned)hx < HH) && ((unsigned)gw < WW);
        const float* xp = x + (size_t)(b * CIN + slot * 8) * HW + (size_t)hx * WW + gw;
        gval[i] = v;
        gdst[i] = (unsigned)(R7_XOFF + ps * R7_ROW + slot * R7_SLOT + wI * 16);
        #pragma unroll
        for (int q = 0; q < 8; ++q) gv[i][q] = inb ? xp[(size_t)q * HW] : 0.f;
      }
    }

    f32x16 acc[2][2];
    #pragma unroll
    for (int mf = 0; mf < 2; ++mf)
      #pragma unroll
      for (int nf = 0; nf < 2; ++nf)
        #pragma unroll
        for (int g = 0; g < 16; ++g)
          acc[mf][nf][g] = bv[mf][g];

    #pragma unroll
    for (int kc = 0; kc < 36; ++kc) {
      const bf16x8 af0 = *(const bf16x8*)(Asb + kc * 2048);
      const bf16x8 af1 = *(const bf16x8*)(Asb + kc * 2048 + 512);
      const unsigned bb = boff_t[kc >> 2] + (unsigned)((kc & 3) * 2 * R7_SLOT);
      const bf16x8 bf0 = *(const bf16x8*)(Bsb + bb);
      const bf16x8 bf1 = *(const bf16x8*)(Bsb + bb + 512);
      acc[0][0] = __builtin_amdgcn_mfma_f32_32x32x16_bf16(af0, bf0, acc[0][0], 0, 0, 0);
      acc[0][1] = __builtin_amdgcn_mfma_f32_32x32x16_bf16(af0, bf1, acc[0][1], 0, 0, 0);
      acc[1][0] = __builtin_amdgcn_mfma_f32_32x32x16_bf16(af1, bf0, acc[1][0], 0, 0, 0);
      acc[1][1] = __builtin_amdgcn_mfma_f32_32x32x16_bf16(af1, bf1, acc[1][1], 0, 0, 0);
    }

    const int hout = hbase + it * 2 + row;
    #pragma unroll
    for (int mf = 0; mf < 2; ++mf)
      #pragma unroll
      for (int nf = 0; nf < 2; ++nf) {
        const f32x16 v = acc[mf][nf];
        float* op = out + (((size_t)(a * NB + b) * COUT + mf * 32 + 4 * half) * HH
                           + hout) * WW + w0 + nf * 32 + ln;
        #pragma unroll
        for (int g = 0; g < 16; ++g)
          __builtin_nontemporal_store(v[g], op + (size_t)((g & 3) + 8 * (g >> 2)) * HW);
      }

    lgkm_barrier();
    if (ngran) {
      #pragma unroll
      for (int i = 0; i < 5; ++i)
        if (gval[i]) {
          uint4 u;
          u.x = pk2(gv[i][0], gv[i][1]); u.y = pk2(gv[i][2], gv[i][3]);
          u.z = pk2(gv[i][4], gv[i][5]); u.w = pk2(gv[i][6], gv[i][7]);
          *(uint4*)(lds + gdst[i]) = u;
        }
    }
    lgkm_barrier();
  }
}

extern "C" void kernel_launch(void* const* d_in, const int* in_sizes, int n_in,
                              void* d_out, int out_size, void* d_ws, size_t ws_size,
                              hipStream_t stream) {
  const float* x    = (const float*)d_in[0];
  const float* wgt  = (const float*)d_in[1];
  const float* bias = (const float*)d_in[2];
  float* out = (float*)d_out;

  const size_t XT_BYTES = (size_t)NB * HH * 8 * 128 * 16;   // 33,554,432
  const size_t A_BYTES  = 75776;

  if (ws_size >= XT_BYTES + A_BYTES) {
    unsigned short* xt = (unsigned short*)d_ws;
    unsigned short* A  = (unsigned short*)((char*)d_ws + XT_BYTES);
    build_A_kernel<<<148, 256, 0, stream>>>(wgt, bias, A);
    xt_build_kernel<<<8192, 256, 0, stream>>>(x, xt);
    aconv_v10_kernel<<<256, 512, 0, stream>>>(xt, A, out);
  } else {
    unsigned short* A = (unsigned short*)d_ws;
    build_A_kernel<<<148, 256, 0, stream>>>(wgt, bias, A);
    aconv_v7_kernel<<<256, 512, 0, stream>>>(x, A, bias, out);
  }
}

// Round 11
// 111.340 us; speedup vs baseline: 1.1134x; 1.1134x over previous
//
#include <hip/hip_runtime.h>

// AdaptiveAngleConv round 11: v9 skeleton (16 waves, gll staging, bias-kstep)
// + dh-sorted tap order (new ring rows first needed at kc12)
// + split fences: mid-K vmcnt(63)+barrier; tile-end lgkm barrier -> glls -> stores.
// NO store drain anywhere in the tile loop.
// Fallback (small ws_size): R7 kernel (101 us).

#define CIN 64
#define COUT 64
#define HH 128
#define WW 128
#define NB 16
#define HW (HH*WW)

typedef short bf16x8 __attribute__((ext_vector_type(8)));
typedef float f32x16 __attribute__((ext_vector_type(16)));
#define AS1 __attribute__((address_space(1)))
#define AS3 __attribute__((address_space(3)))

// dh-sorted tap tables (j = 0..8, dh(j) = j/3 by construction):
// AOFF_d[a][j] = sorted_s * 8192 (A slab byte offset); DWBS_d[a][j] = dw*16 bytes.
__device__ __constant__ unsigned AOFF_d[4][9] = {
  {0, 8192, 16384, 24576, 32768, 40960, 49152, 57344, 65536},
  {0, 8192, 24576, 16384, 32768, 49152, 40960, 57344, 65536},
  {0, 24576, 49152, 8192, 32768, 57344, 16384, 40960, 65536},
  {24576, 49152, 57344, 0, 32768, 65536, 8192, 16384, 40960},
};
__device__ __constant__ unsigned short DWBS_d[4][9] = {
  {0,16,32, 0,16,32, 0,16,32},
  {16,32,0, 32,16,0, 32,0,16},
  {32,16,0, 32,16,0, 32,16,0},
  {32,16,0, 32,16,0, 32,16,0},
};
// (R7 fallback tables, s-indexed)
__device__ __constant__ unsigned char DHI_d[4][9] = {
  {0,0,0,1,1,1,2,2,2},
  {0,0,1,0,1,2,1,2,2},
  {0,1,2,0,1,2,0,1,2},
  {1,2,2,0,1,2,0,0,1},
};
__device__ __constant__ unsigned short DWB_d[4][9] = {
  {0,16,32,0,16,32,0,16,32},
  {16,32,32,0,16,32,0,0,16},
  {32,32,32,16,16,16,0,0,0},
  {32,32,16,32,16,0,16,0,0},
};

static __device__ __forceinline__ unsigned short f2bf(float f) {
  unsigned u = __builtin_bit_cast(unsigned, f);
  return (unsigned short)((u + 0x7FFFu + ((u >> 16) & 1u)) >> 16);
}
static __device__ __forceinline__ unsigned pk2(float lo, float hi) {
  return (unsigned)f2bf(lo) | ((unsigned)f2bf(hi) << 16);
}

// ---- pass 1: x transpose/convert. granule idx = ((b*HH+h)*8+slot)*128 + w ----
__global__ __launch_bounds__(256) void xt_build_kernel(const float* __restrict__ x,
                                                       unsigned short* __restrict__ xt) {
  const int gid = blockIdx.x * 256 + threadIdx.x;   // 2,097,152
  const int w = gid & 127;
  const int h = (gid >> 7) & 127;
  const int slot = (gid >> 14) & 7;
  const int b = gid >> 17;
  const float* xp = x + ((size_t)(b * CIN + slot * 8) * HH + h) * WW + w;
  uint4 u;
  u.x = pk2(xp[0], xp[HW]);
  u.y = pk2(xp[2 * HW], xp[3 * HW]);
  u.z = pk2(xp[4 * HW], xp[5 * HW]);
  u.w = pk2(xp[6 * HW], xp[7 * HW]);
  const size_t idx = ((size_t)(b * HH + h) * 8 + slot) * 128 + w;
  *(uint4*)((unsigned char*)xt + idx * 16) = u;
}

// ---- pass 2: canonical A + bias kstep. 37,888 bf16 ----
__global__ void build_A_kernel(const float* __restrict__ wgt,
                               const float* __restrict__ bias,
                               unsigned short* __restrict__ A) {
  const int e = blockIdx.x * 256 + threadIdx.x;
  const int j = e & 7;
  const int cm = (e >> 3) & 63;
  const int half = (e >> 9) & 1;
  const int kc = e >> 10;
  if (kc < 36) {
    const int s = kc >> 2, q = kc & 3;
    const int ci = q * 16 + half * 8 + j;
    A[e] = f2bf(wgt[(cm * CIN + ci) * 9 + s]);
  } else if (kc == 36) {
    A[e] = (half == 0 && j == 0) ? f2bf(bias[cm]) : (unsigned short)0;
  }
}

// =======================  v11 main kernel  =======================
#define V9_SLOT 2080
#define V9_ROW  16640               // 8 * V9_SLOT
#define V9_XOFF 75776               // 37 kc * 2048 B
#define V9_LDS  (V9_XOFF + 4 * V9_ROW)   // 142,336 B

__global__ __launch_bounds__(1024, 4) void aconv_v11_kernel(
    const unsigned short* __restrict__ xt,    // granules [b][h][slot][w]
    const unsigned short* __restrict__ Ag,    // 37 kc canonical + bias
    float* __restrict__ out)                  // [4][B][COUT][H][W] fp32
{
  __shared__ __align__(16) unsigned char lds[V9_LDS];

  const int tid = threadIdx.x;
  const int lane = tid & 63;
  const int wid = tid >> 6;          // 16 waves
  const int a   = wid >> 2;          // angle
  const int row = (wid >> 1) & 1;    // row within 2-row tile
  const int wh  = wid & 1;           // w half
  const int half = lane >> 5;
  const int ln = lane & 31;

  const int b   = blockIdx.x >> 4;
  const int rem = blockIdx.x & 15;
  const int hbase = rem * 8;

  const unsigned char* Agb = (const unsigned char*)Ag;
  const unsigned char* xtb = (const unsigned char*)xt;
  AS3 unsigned char* ldsa = (AS3 unsigned char*)lds;
  const uint4 z4 = {0u, 0u, 0u, 0u};

  unsigned aoff[9]; unsigned short dwbs[9];
  #pragma unroll
  for (int j = 0; j < 9; ++j) { aoff[j] = AOFF_d[a][j]; dwbs[j] = DWBS_d[a][j]; }

  // ---- prologue: A (74 gll), border zeros, x rows hbase-1..+2 (64 gll) ----
  #pragma unroll
  for (int j = 0; j < 5; ++j) {
    const int i = wid + j * 16;
    if (i < 74)
      __builtin_amdgcn_global_load_lds(
          (const AS1 unsigned*)(Agb + i * 1024 + lane * 16),
          (AS3 unsigned*)(ldsa + i * 1024), 16, 0, 0);
  }
  if (tid < 64) {
    const int rs = tid >> 4, cs = (tid >> 1) & 7, side = tid & 1;
    *(uint4*)(lds + V9_XOFF + rs * V9_ROW + cs * V9_SLOT + side * 129 * 16) = z4;
  }
  #pragma unroll
  for (int j = 0; j < 4; ++j) {
    const int c = wid + j * 16;        // 64 combos: 4 rows x 8 slots x 2 halves
    const int rr = c >> 4;
    const int s  = (c >> 1) & 7;
    const int k  = c & 1;
    const int gh = hbase - 1 + rr;
    const unsigned dst = (unsigned)(V9_XOFF + rr * V9_ROW + s * V9_SLOT + 16 + k * 1024);
    if (gh >= 0) {
      __builtin_amdgcn_global_load_lds(
          (const AS1 unsigned*)(xtb + ((size_t)((b * HH + gh) * 8 + s) * 128 + k * 64) * 16 + lane * 16),
          (AS3 unsigned*)(ldsa + dst), 16, 0, 0);
    } else {
      *(uint4*)(lds + dst + lane * 16) = z4;
    }
  }
  __syncthreads();   // drains vmcnt + lgkm; per-wave VMEM queue empty here

  const unsigned char* Asb = lds + (unsigned)(half * 1024 + ln * 16);
  const unsigned char* Bsb = lds + V9_XOFF + (unsigned)(half * V9_SLOT + (wh * 64 + ln) * 16);

  bf16x8 ob = (bf16x8)(short)0;      // one-hot B frag for bias kstep
  if (half == 0) ob[0] = (short)0x3F80;

  #pragma unroll 1
  for (int it = 0; it < 4; ++it) {
    // sorted-tap B offsets: dh(j) = j/3 -> ring slot (it*2+row+j/3)&3
    unsigned boff_t[9];
    #pragma unroll
    for (int j = 0; j < 9; ++j)
      boff_t[j] = (unsigned)dwbs[j]
                + (unsigned)(((it * 2 + row + (j / 3)) & 3) * V9_ROW);

    f32x16 acc[2][2];
    #pragma unroll
    for (int mf = 0; mf < 2; ++mf)
      #pragma unroll
      for (int nf = 0; nf < 2; ++nf) acc[mf][nf] = (f32x16)(0.f);

    #pragma unroll
    for (int j = 0; j < 9; ++j) {
      if (j == 3) {
        // rows staged last tile become visible: my glls are all but the
        // newest 64 VMEM ops (the NT stores issued after them) -> vmcnt(63).
        asm volatile("s_waitcnt vmcnt(63)" ::: "memory");
        __builtin_amdgcn_s_barrier();
      }
      #pragma unroll
      for (int q = 0; q < 4; ++q) {
        const bf16x8 af0 = *(const bf16x8*)(Asb + aoff[j] + q * 2048);
        const bf16x8 af1 = *(const bf16x8*)(Asb + aoff[j] + q * 2048 + 512);
        const unsigned bb = boff_t[j] + (unsigned)(q * 2 * V9_SLOT);
        const bf16x8 bf0 = *(const bf16x8*)(Bsb + bb);
        const bf16x8 bf1 = *(const bf16x8*)(Bsb + bb + 512);
        acc[0][0] = __builtin_amdgcn_mfma_f32_32x32x16_bf16(af0, bf0, acc[0][0], 0, 0, 0);
        acc[0][1] = __builtin_amdgcn_mfma_f32_32x32x16_bf16(af0, bf1, acc[0][1], 0, 0, 0);
        acc[1][0] = __builtin_amdgcn_mfma_f32_32x32x16_bf16(af1, bf0, acc[1][0], 0, 0, 0);
        acc[1][1] = __builtin_amdgcn_mfma_f32_32x32x16_bf16(af1, bf1, acc[1][1], 0, 0, 0);
      }
    }
    {  // bias kstep: one-hot B adds bias[cm] to every column
      const bf16x8 af0 = *(const bf16x8*)(Asb + 36 * 2048);
      const bf16x8 af1 = *(const bf16x8*)(Asb + 36 * 2048 + 512);
      acc[0][0] = __builtin_amdgcn_mfma_f32_32x32x16_bf16(af0, ob, acc[0][0], 0, 0, 0);
      acc[0][1] = __builtin_amdgcn_mfma_f32_32x32x16_bf16(af0, ob, acc[0][1], 0, 0, 0);
      acc[1][0] = __builtin_amdgcn_mfma_f32_32x32x16_bf16(af1, ob, acc[1][0], 0, 0, 0);
      acc[1][1] = __builtin_amdgcn_mfma_f32_32x32x16_bf16(af1, ob, acc[1][1], 0, 0, 0);
    }

    // tile-end fence: all waves done reading the ring (lgkm only, no store drain)
    asm volatile("s_waitcnt lgkmcnt(0)" ::: "memory");
    __builtin_amdgcn_s_barrier();

    // restage 2 rows into the 2 just-freed slots, BEFORE the stores
    // (queue per wave this tile: [gll x2, stores x64])
    if (it < 3) {
      #pragma unroll
      for (int j = 0; j < 2; ++j) {
        const int c = wid + j * 16;     // 32 combos: 2 rows x 8 slots x 2 halves
        const int rr = c >> 4;
        const int s  = (c >> 1) & 7;
        const int k  = c & 1;
        const int gh = hbase + it * 2 + 3 + rr;
        const unsigned dst = (unsigned)(V9_XOFF + ((it * 2 + rr) & 3) * V9_ROW
                                        + s * V9_SLOT + 16 + k * 1024);
        if (gh < HH) {
          __builtin_amdgcn_global_load_lds(
              (const AS1 unsigned*)(xtb + ((size_t)((b * HH + gh) * 8 + s) * 128 + k * 64) * 16 + lane * 16),
              (AS3 unsigned*)(ldsa + dst), 16, 0, 0);
        } else {
          *(uint4*)(lds + dst + lane * 16) = z4;
        }
      }
    }

    // NT stores (fire-and-forget; drain under next tile's K-loop)
    const int hout = hbase + it * 2 + row;
    #pragma unroll
    for (int mf = 0; mf < 2; ++mf)
      #pragma unroll
      for (int nf = 0; nf < 2; ++nf) {
        const f32x16 v = acc[mf][nf];
        float* op = out + (((size_t)(a * NB + b) * COUT + mf * 32 + 4 * half) * HH
                           + hout) * WW + wh * 64 + nf * 32 + ln;
        #pragma unroll
        for (int g = 0; g < 16; ++g)
          __builtin_nontemporal_store(v[g], op + (size_t)((g & 3) + 8 * (g >> 2)) * HW);
      }
  }
}

// =======================  R7 fallback kernel  =======================
#define R7_SLOT 1072
#define R7_ROW  8576
#define R7_XOFF 73728
#define R7_LDS  (R7_XOFF + 4 * R7_ROW)

static __device__ __forceinline__ void lgkm_barrier() {
  asm volatile("s_waitcnt lgkmcnt(0)" ::: "memory");
  __builtin_amdgcn_s_barrier();
}

__global__ __launch_bounds__(512) void aconv_v7_kernel(
    const float* __restrict__ x,
    const unsigned short* __restrict__ Ag,
    const float* __restrict__ bias,
    float* __restrict__ out)
{
  __shared__ __align__(16) unsigned char lds[R7_LDS];

  const int tid = threadIdx.x;
  const int lane = tid & 63;
  const int wid = tid >> 6;
  const int a   = wid >> 1;
  const int row = wid & 1;
  const int half = lane >> 5;
  const int ln = lane & 31;

  const int blk = blockIdx.x;
  const int b   = blk >> 4;
  const int rem = blk & 15;
  const int hbase = rem * 8;

  float bv[2][16];
  #pragma unroll
  for (int mf = 0; mf < 2; ++mf)
    #pragma unroll
    for (int g = 0; g < 16; ++g)
      bv[mf][g] = bias[mf * 32 + (g & 3) + 8 * (g >> 2) + 4 * half];

  int dhi[9]; unsigned dwb[9];
  #pragma unroll
  for (int s = 0; s < 9; ++s) { dhi[s] = DHI_d[a][s]; dwb[s] = DWB_d[a][s]; }

  {
    const uint4* Ag4 = (const uint4*)Ag;
    uint4* As4 = (uint4*)lds;
    #pragma unroll
    for (int i = 0; i < 9; ++i) As4[tid + i * 512] = Ag4[tid + i * 512];
  }

  float gv[5][8];
  unsigned gdst[5];
  bool gval[5];

  #pragma unroll
  for (int i = 0; i < 5; ++i) {
    const int g = tid + i * 512;
    const bool v = g < 2112;
    const int rg = g / 528;
    const int rest = g - rg * 528;
    const int slot = rest / 66;
    const int wI = rest - slot * 66;
    const int hx = hbase - 1 + rg;
    const int gw = -1 + wI;
    const bool inb = v && ((unsigned)hx < HH) && ((unsigned)gw < WW);
    const float* xp = x + (size_t)(b * CIN + slot * 8) * HW + (size_t)hx * WW + gw;
    gval[i] = v;
    gdst[i] = (unsigned)(R7_XOFF + rg * R7_ROW + slot * R7_SLOT + wI * 16);
    #pragma unroll
    for (int q = 0; q < 8; ++q) gv[i][q] = inb ? xp[(size_t)q * HW] : 0.f;
  }
  #pragma unroll
  for (int i = 0; i < 5; ++i)
    if (gval[i]) {
      uint4 u;
      u.x = pk2(gv[i][0], gv[i][1]); u.y = pk2(gv[i][2], gv[i][3]);
      u.z = pk2(gv[i][4], gv[i][5]); u.w = pk2(gv[i][6], gv[i][7]);
      *(uint4*)(lds + gdst[i]) = u;
    }
  __syncthreads();

  const unsigned char* Asb = lds + (unsigned)(half * 1024 + ln * 16);
  const unsigned char* Bsb = lds + R7_XOFF + (unsigned)(half * R7_SLOT + ln * 16);

  #pragma unroll 1
  for (int ti = 0; ti < 8; ++ti) {
    const int wh = ti >> 2, it = ti & 3;
    const int w0 = wh * 64;

    unsigned boff_t[9];
    {
      unsigned rowoff[3];
      #pragma unroll
      for (int dh = 0; dh < 3; ++dh)
        rowoff[dh] = (unsigned)(((2 * it + row + dh) & 3) * R7_ROW);
      #pragma unroll
      for (int s = 0; s < 9; ++s) boff_t[s] = dwb[s] + rowoff[dhi[s]];
    }

    const bool pf2 = (it < 3);
    const bool pf4 = (it == 3) && (wh == 0);
    const int ngran = pf2 ? 1056 : (pf4 ? 2112 : 0);
    if (ngran) {
      const int itv = pf4 ? -2 : it;
      const int w0n = pf4 ? 64 : w0;
      #pragma unroll
      for (int i = 0; i < 5; ++i) {
        const int g = tid + i * 512;
        const bool v = g < ngran;
        const int rg = g / 528;
        const int rest = g - rg * 528;
        const int slot = rest / 66;
        const int wI = rest - slot * 66;
        const int hx = hbase + 2 * itv + 3 + rg;
        const int ps = (2 * itv + 4 + rg) & 3;
        const int gw = w0n - 1 + wI;
        const bool inb = v && ((unsigned)hx < HH) && ((unsigned)gw < WW);
        const float* xp = x + (size_t)(b * CIN + slot * 8) * HW + (size_t)hx * WW + gw;
        gval[i] = v;
        gdst[i] = (unsigned)(R7_XOFF + ps * R7_ROW + slot * R7_SLOT + wI * 16);
        #pragma unroll
        for (int q = 0; q < 8; ++q) gv[i][q] = inb ? xp[(size_t)q * HW] : 0.f;
      }
    }

    f32x16 acc[2][2];
    #pragma unroll
    for (int mf = 0; mf < 2; ++mf)
      #pragma unroll
      for (int nf = 0; nf < 2; ++nf)
        #pragma unroll
        for (int g = 0; g < 16; ++g)
          acc[mf][nf][g] = bv[mf][g];

    #pragma unroll
    for (int kc = 0; kc < 36; ++kc) {
      const bf16x8 af0 = *(const bf16x8*)(Asb + kc * 2048);
      const bf16x8 af1 = *(const bf16x8*)(Asb + kc * 2048 + 512);
      const unsigned bb = boff_t[kc >> 2] + (unsigned)((kc & 3) * 2 * R7_SLOT);
      const bf16x8 bf0 = *(const bf16x8*)(Bsb + bb);
      const bf16x8 bf1 = *(const bf16x8*)(Bsb + bb + 512);
      acc[0][0] = __builtin_amdgcn_mfma_f32_32x32x16_bf16(af0, bf0, acc[0][0], 0, 0, 0);
      acc[0][1] = __builtin_amdgcn_mfma_f32_32x32x16_bf16(af0, bf1, acc[0][1], 0, 0, 0);
      acc[1][0] = __builtin_amdgcn_mfma_f32_32x32x16_bf16(af1, bf0, acc[1][0], 0, 0, 0);
      acc[1][1] = __builtin_amdgcn_mfma_f32_32x32x16_bf16(af1, bf1, acc[1][1], 0, 0, 0);
    }

    const int hout = hbase + it * 2 + row;
    #pragma unroll
    for (int mf = 0; mf < 2; ++mf)
      #pragma unroll
      for (int nf = 0; nf < 2; ++nf) {
        const f32x16 v = acc[mf][nf];
        float* op = out + (((size_t)(a * NB + b) * COUT + mf * 32 + 4 * half) * HH
                           + hout) * WW + w0 + nf * 32 + ln;
        #pragma unroll
        for (int g = 0; g < 16; ++g)
          __builtin_nontemporal_store(v[g], op + (size_t)((g & 3) + 8 * (g >> 2)) * HW);
      }

    lgkm_barrier();
    if (ngran) {
      #pragma unroll
      for (int i = 0; i < 5; ++i)
        if (gval[i]) {
          uint4 u;
          u.x = pk2(gv[i][0], gv[i][1]); u.y = pk2(gv[i][2], gv[i][3]);
          u.z = pk2(gv[i][4], gv[i][5]); u.w = pk2(gv[i][6], gv[i][7]);
          *(uint4*)(lds + gdst[i]) = u;
        }
    }
    lgkm_barrier();
  }
}

extern "C" void kernel_launch(void* const* d_in, const int* in_sizes, int n_in,
                              void* d_out, int out_size, void* d_ws, size_t ws_size,
                              hipStream_t stream) {
  const float* x    = (const float*)d_in[0];
  const float* wgt  = (const float*)d_in[1];
  const float* bias = (const float*)d_in[2];
  float* out = (float*)d_out;

  const size_t XT_BYTES = (size_t)NB * HH * 8 * 128 * 16;   // 33,554,432
  const size_t A_BYTES  = 75776;

  if (ws_size >= XT_BYTES + A_BYTES) {
    unsigned short* xt = (unsigned short*)d_ws;
    unsigned short* A  = (unsigned short*)((char*)d_ws + XT_BYTES);
    build_A_kernel<<<148, 256, 0, stream>>>(wgt, bias, A);
    xt_build_kernel<<<8192, 256, 0, stream>>>(x, xt);
    aconv_v11_kernel<<<256, 1024, 0, stream>>>(xt, A, out);
  } else {
    unsigned short* A = (unsigned short*)d_ws;
    build_A_kernel<<<148, 256, 0, stream>>>(wgt, bias, A);
    aconv_v7_kernel<<<256, 512, 0, stream>>>(x, A, bias, out);
  }
}

// Round 12
// 107.445 us; speedup vs baseline: 1.1538x; 1.0362x over previous
//
#include <hip/hip_runtime.h>

// AdaptiveAngleConv round 12: whole-strip LDS residency, 16 waves, no xt pass.
//   pass 1: build_A — canonical weights + bias as 37th K-step (validated).
//   pass 2: aconv_v12 — 256 blocks x 1024 thr (16 waves/CU = 4/SIMD).
//     LDS: A (37 kc, 75,776 B) + 10 half-width x rows (85,760 B) = 161,536 B.
//     Flow: stage strip wh=0 (fp32 reg-staged, in-kernel bf16 convert) -> sync
//           -> tile(0) -> tile(1)   [NO barriers: LDS read-only]
//           -> lgkm barrier -> restage strip wh=1 -> lgkm barrier
//           -> tile(0) -> tile(1).
//     Waves = (angle 0..3) x (row 0..3); wave tile M=64 x N=64 (acc 64 AGPR).
//     NT stores fire-and-forget. Only 3 barriers total.

#define CIN 64
#define COUT 64
#define HH 128
#define WW 128
#define NB 16
#define HW (HH*WW)

typedef short bf16x8 __attribute__((ext_vector_type(8)));
typedef float f32x16 __attribute__((ext_vector_type(16)));
#define AS1 __attribute__((address_space(1)))
#define AS3 __attribute__((address_space(3)))

// DOFF_d[a][s] = dh*8576 + dw*16 for x-tap INV_a[s] paired with weight-tap s
// (== R4/R5/R7-validated BOFF table, XS_ROW = 8576).
__device__ __constant__ unsigned DOFF_d[4][9] = {
  {0,16,32,8576,8592,8608,17152,17168,17184},
  {16,32,8608,0,8592,17184,8576,17152,17168},
  {32,8608,17184,16,8592,17168,0,8576,17152},
  {8608,17184,17168,32,8592,17152,16,0,8576},
};

static __device__ __forceinline__ unsigned short f2bf(float f) {
  unsigned u = __builtin_bit_cast(unsigned, f);
  return (unsigned short)((u + 0x7FFFu + ((u >> 16) & 1u)) >> 16);
}
static __device__ __forceinline__ unsigned pk2(float lo, float hi) {
  return (unsigned)f2bf(lo) | ((unsigned)f2bf(hi) << 16);
}

// Canonical A + bias kstep (v9-validated): e = ((kc*2 + half)*64 + cm)*8 + j.
// kc<36: ci = (kc&3)*16 + half*8 + j, value W[cm][ci][kc>>2].
// kc==36: bias[cm] one-hot at (half==0, j==0). 37,888 bf16 = 75,776 B.
__global__ void build_A_kernel(const float* __restrict__ wgt,
                               const float* __restrict__ bias,
                               unsigned short* __restrict__ A) {
  const int e = blockIdx.x * 256 + threadIdx.x;
  const int j = e & 7;
  const int cm = (e >> 3) & 63;
  const int half = (e >> 9) & 1;
  const int kc = e >> 10;
  if (kc < 36) {
    const int s = kc >> 2, q = kc & 3;
    const int ci = q * 16 + half * 8 + j;
    A[e] = f2bf(wgt[(cm * CIN + ci) * 9 + s]);
  } else if (kc == 36) {
    A[e] = (half == 0 && j == 0) ? f2bf(bias[cm]) : (unsigned short)0;
  }
}

static __device__ __forceinline__ void lgkm_barrier() {
  asm volatile("s_waitcnt lgkmcnt(0)" ::: "memory");
  __builtin_amdgcn_s_barrier();
}

// x strip layout (R7-proven conflict-free): byte(r, ci, wI) =
//   XS_OFF + r*XS_ROW + (ci>>3)*XS_SLOT + wI*16 + (ci&7)*2
//   r = 0..9 (x rows hbase-1 .. hbase+8), wI = 0..65 (cols w0-1 .. w0+64)
#define XS_SLOT 1072
#define XS_ROW  8576
#define XS_OFF  75776
#define LDS_BYTES (XS_OFF + 10 * XS_ROW)   // 161,536 B (<= 163,840)

__global__ __launch_bounds__(1024, 4) void aconv_v12_kernel(
    const float* __restrict__ x,              // [B][CIN][H][W] fp32
    const unsigned short* __restrict__ Ag,    // 37 kc canonical + bias
    float* __restrict__ out)                  // [4][B][COUT][H][W] fp32
{
  __shared__ __align__(16) unsigned char lds[LDS_BYTES];

  const int tid = threadIdx.x;
  const int lane = tid & 63;
  const int wid = tid >> 6;          // 16 waves
  const int a   = wid >> 2;          // angle
  const int row = wid & 3;           // output row within 4-row tile
  const int half = lane >> 5;
  const int ln = lane & 31;

  const int b   = blockIdx.x >> 4;
  const int rem = blockIdx.x & 15;
  const int hbase = rem * 8;

  const unsigned char* Agb = (const unsigned char*)Ag;
  AS3 unsigned char* ldsa = (AS3 unsigned char*)lds;

  unsigned doff[9];
  #pragma unroll
  for (int s = 0; s < 9; ++s) doff[s] = DOFF_d[a][s];

  // ---- stage A via global_load_lds (zero staging VGPRs; 74 x 1024 B) ----
  #pragma unroll
  for (int j = 0; j < 5; ++j) {
    const int i = wid + j * 16;
    if (i < 74)
      __builtin_amdgcn_global_load_lds(
          (const AS1 unsigned*)(Agb + i * 1024 + lane * 16),
          (AS3 unsigned*)(ldsa + i * 1024), 16, 0, 0);
  }

  // ---- strip stager: 10 rows x 8 slots x 66 cols = 5280 granules (16 B) ----
  auto stage = [&](int w0) {
    #pragma unroll
    for (int i = 0; i < 6; ++i) {
      const int g = tid + i * 1024;
      if (g < 5280) {
        const int r    = g / 528;
        const int rest = g - r * 528;
        const int slot = rest / 66;
        const int wI   = rest - slot * 66;
        const int gh = hbase - 1 + r;
        const int gw = w0 - 1 + wI;
        const bool inb = ((unsigned)gh < HH) && ((unsigned)gw < WW);
        const float* xp = x + (size_t)(b * CIN + slot * 8) * HW + (size_t)gh * WW + gw;
        float v[8];
        #pragma unroll
        for (int q = 0; q < 8; ++q) v[q] = inb ? xp[(size_t)q * HW] : 0.f;
        uint4 u;
        u.x = pk2(v[0], v[1]); u.y = pk2(v[2], v[3]);
        u.z = pk2(v[4], v[5]); u.w = pk2(v[6], v[7]);
        *(uint4*)(lds + XS_OFF + r * XS_ROW + slot * XS_SLOT + wI * 16) = u;
      }
    }
  };

  const unsigned char* Asb = lds + (unsigned)(half * 1024 + ln * 16);
  const unsigned char* Bsb = lds + XS_OFF + (unsigned)(half * XS_SLOT + ln * 16);

  bf16x8 ob = (bf16x8)(short)0;      // one-hot B frag for bias kstep
  if (half == 0) ob[0] = (short)0x3F80;

  // ---- per-tile compute: output rows hbase + it*4 + row, cols w0..w0+63 ----
  auto tile = [&](int it, int w0) {
    const unsigned rowbyte = (unsigned)((it * 4 + row) * XS_ROW);

    f32x16 acc[2][2];
    #pragma unroll
    for (int mf = 0; mf < 2; ++mf)
      #pragma unroll
      for (int nf = 0; nf < 2; ++nf) acc[mf][nf] = (f32x16)(0.f);

    #pragma unroll
    for (int s = 0; s < 9; ++s) {
      const unsigned bjs = doff[s] + rowbyte;
      #pragma unroll
      for (int q = 0; q < 4; ++q) {
        const bf16x8 af0 = *(const bf16x8*)(Asb + (s * 4 + q) * 2048);
        const bf16x8 af1 = *(const bf16x8*)(Asb + (s * 4 + q) * 2048 + 512);
        const unsigned bb = bjs + (unsigned)(q * 2 * XS_SLOT);
        const bf16x8 bf0 = *(const bf16x8*)(Bsb + bb);
        const bf16x8 bf1 = *(const bf16x8*)(Bsb + bb + 512);
        acc[0][0] = __builtin_amdgcn_mfma_f32_32x32x16_bf16(af0, bf0, acc[0][0], 0, 0, 0);
        acc[0][1] = __builtin_amdgcn_mfma_f32_32x32x16_bf16(af0, bf1, acc[0][1], 0, 0, 0);
        acc[1][0] = __builtin_amdgcn_mfma_f32_32x32x16_bf16(af1, bf0, acc[1][0], 0, 0, 0);
        acc[1][1] = __builtin_amdgcn_mfma_f32_32x32x16_bf16(af1, bf1, acc[1][1], 0, 0, 0);
      }
    }
    {  // bias kstep: one-hot B adds bias[cm] to every column
      const bf16x8 af0 = *(const bf16x8*)(Asb + 36 * 2048);
      const bf16x8 af1 = *(const bf16x8*)(Asb + 36 * 2048 + 512);
      acc[0][0] = __builtin_amdgcn_mfma_f32_32x32x16_bf16(af0, ob, acc[0][0], 0, 0, 0);
      acc[0][1] = __builtin_amdgcn_mfma_f32_32x32x16_bf16(af0, ob, acc[0][1], 0, 0, 0);
      acc[1][0] = __builtin_amdgcn_mfma_f32_32x32x16_bf16(af1, ob, acc[1][0], 0, 0, 0);
      acc[1][1] = __builtin_amdgcn_mfma_f32_32x32x16_bf16(af1, ob, acc[1][1], 0, 0, 0);
    }

    // NT stores, fire-and-forget
    const int hout = hbase + it * 4 + row;
    #pragma unroll
    for (int mf = 0; mf < 2; ++mf)
      #pragma unroll
      for (int nf = 0; nf < 2; ++nf) {
        const f32x16 v = acc[mf][nf];
        float* op = out + (((size_t)(a * NB + b) * COUT + mf * 32 + 4 * half) * HH
                           + hout) * WW + w0 + nf * 32 + ln;
        #pragma unroll
        for (int g = 0; g < 16; ++g)
          __builtin_nontemporal_store(v[g], op + (size_t)((g & 3) + 8 * (g >> 2)) * HW);
      }
  };

  // ---- flow ----
  stage(0);
  __syncthreads();                   // drains A glls (vmcnt) + x ds_writes (lgkm)

  tile(0, 0);
  tile(1, 0);

  lgkm_barrier();                    // all waves done reading strip 0
  stage(64);                         // restage; compiler waits loads before packs
  lgkm_barrier();                    // strip 1 visible

  tile(0, 64);
  tile(1, 64);
}

extern "C" void kernel_launch(void* const* d_in, const int* in_sizes, int n_in,
                              void* d_out, int out_size, void* d_ws, size_t ws_size,
                              hipStream_t stream) {
  const float* x    = (const float*)d_in[0];
  const float* wgt  = (const float*)d_in[1];
  const float* bias = (const float*)d_in[2];
  float* out = (float*)d_out;
  unsigned short* A = (unsigned short*)d_ws;   // 75,776 B

  build_A_kernel<<<148, 256, 0, stream>>>(wgt, bias, A);
  aconv_v12_kernel<<<256, 1024, 0, stream>>>(x, A, out);
}